// Round 1
// baseline (769.274 us; speedup 1.0000x reference)
//
#include <hip/hip_runtime.h>

typedef unsigned short u16;
typedef __bf16  bf16x8 __attribute__((ext_vector_type(8)));
typedef float   f32x4  __attribute__((ext_vector_type(4)));
typedef unsigned int   u32x4 __attribute__((ext_vector_type(4)));
typedef unsigned short u16x4 __attribute__((ext_vector_type(4)));

#define BB 2
#define HH 16
#define DD 64
#define SS 2048
#define EE 1024

// ---------- helpers ----------
static __device__ __forceinline__ u16 f2bf(float f) {
    unsigned int u = __float_as_uint(f);
    u += 0x7FFFu + ((u >> 16) & 1u);          // round-to-nearest-even
    return (u16)(u >> 16);
}

union BfCast { u32x4 u; bf16x8 b; };
static __device__ __forceinline__ bf16x8 ldb8(const u16* p) {
    BfCast x; x.u = *(const u32x4*)p; return x.b;
}

// ---------- 1. fp32 -> bf16 convert (x) ----------
__global__ __launch_bounds__(256) void conv_kernel(
    const float* __restrict__ in, u16* __restrict__ out, int n4)
{
    int i = blockIdx.x * blockDim.x + threadIdx.x;
    if (i < n4) {
        f32x4 v = ((const f32x4*)in)[i];
        u16x4 o;
        o[0] = f2bf(v[0]); o[1] = f2bf(v[1]); o[2] = f2bf(v[2]); o[3] = f2bf(v[3]);
        ((u16x4*)out)[i] = o;
    }
}

// ---------- 2. transpose + convert: in[R][C] fp32 -> out[C][R] bf16 ----------
__global__ __launch_bounds__(256) void transpose_kernel(
    const float* __restrict__ in, u16* __restrict__ out, int R, int C)
{
    __shared__ float tile[32][33];
    const int tx = threadIdx.x & 31;
    const int ty = threadIdx.x >> 5;          // 0..7
    const int ct = C >> 5;
    const int bc = blockIdx.x % ct;
    const int br = blockIdx.x / ct;
    const int c0 = bc * 32, r0 = br * 32;
    #pragma unroll
    for (int i = 0; i < 4; i++)
        tile[ty + i * 8][tx] = in[(r0 + ty + i * 8) * C + c0 + tx];
    __syncthreads();
    #pragma unroll
    for (int i = 0; i < 4; i++)
        out[(c0 + ty + i * 8) * R + r0 + tx] = f2bf(tile[tx][ty + i * 8]);
}

// ---------- 3. QKV GEMM: [4096,1024] x [1024,3072] + bias -> Q,K [B,H,S,D], V [B,H,D,S] ----------
__global__ __launch_bounds__(256) void gemm_qkv_kernel(
    const u16* __restrict__ A,   // x bf16 [4096][1024]
    const u16* __restrict__ BT,  // W_qkv^T bf16 [3072][1024]
    const float* __restrict__ bias,
    u16* __restrict__ Qb, u16* __restrict__ Kb, u16* __restrict__ Vb)
{
    const int K = EE;            // 1024
    const int NT = 3 * EE / 16;  // 192
    const int lane = threadIdx.x & 63;
    const int wave = threadIdx.x >> 6;
    const int t = blockIdx.x * 4 + wave;
    const int tm = t / NT, tn = t % NT;
    const int lm = lane & 15, quad = lane >> 4;
    const u16* ap = A  + (tm * 16 + lm) * K + quad * 8;
    const u16* bp = BT + (tn * 16 + lm) * K + quad * 8;
    f32x4 acc = {0.f, 0.f, 0.f, 0.f};
    #pragma unroll 4
    for (int k0 = 0; k0 < K; k0 += 32)
        acc = __builtin_amdgcn_mfma_f32_16x16x32_bf16(ldb8(ap + k0), ldb8(bp + k0), acc, 0, 0, 0);

    const int n = tn * 16 + lm;
    const float bv = bias[n];
    const int which = n >> 10;       // 0=q 1=k 2=v
    const int e = n & 1023;
    const int h = e >> 6, d = e & 63;
    #pragma unroll
    for (int r = 0; r < 4; r++) {
        const int m = tm * 16 + quad * 4 + r;
        const int b = m >> 11, s = m & 2047;
        const u16 val = f2bf(acc[r] + bv);
        const int bh = b * HH + h;
        if (which == 0)      Qb[(bh * SS + s) * DD + d] = val;
        else if (which == 1) Kb[(bh * SS + s) * DD + d] = val;
        else                 Vb[(bh * DD + d) * SS + s] = val;  // V transposed
    }
}

// ---------- 4. causal flash attention: 1 wave per (b,h, 16-row q-tile) ----------
__global__ __launch_bounds__(64) void attn_kernel(
    const u16* __restrict__ Qb, const u16* __restrict__ Kb,
    const u16* __restrict__ Vb, u16* __restrict__ Ob)   // Ob: [B*S][E] bf16
{
    __shared__ __align__(16) u16 Plds[16 * 32];
    const int lane = threadIdx.x;
    const int lm = lane & 15, quad = lane >> 4;
    const int qt = blockIdx.x & (SS / 16 - 1);
    const int bh = blockIdx.x >> 7;            // B*H = 32
    const int q0 = qt * 16;
    const int b = bh >> 4, h = bh & 15;

    const u16* qbase = Qb + (bh * SS + q0) * DD;
    const bf16x8 qf0 = ldb8(qbase + lm * DD + quad * 8);
    const bf16x8 qf1 = ldb8(qbase + lm * DD + 32 + quad * 8);

    f32x4 o0 = {0,0,0,0}, o1 = {0,0,0,0}, o2 = {0,0,0,0}, o3 = {0,0,0,0};
    float mr[4] = {-INFINITY, -INFINITY, -INFINITY, -INFINITY};
    float lr[4] = {0.f, 0.f, 0.f, 0.f};

    const u16* kbase = Kb + bh * SS * DD;
    const u16* vbase = Vb + bh * DD * SS;
    const float scale = 0.125f;                // 1/sqrt(64)

    const int ktiles = (q0 >> 5) + 1;          // all tiles with k0 <= q0
    for (int kt = 0; kt < ktiles; ++kt) {
        const int k0 = kt * 32;
        // S = Q K^T  (two 16-key halves, contraction D=64 in 2 steps)
        f32x4 s0 = {0,0,0,0}, s1 = {0,0,0,0};
        {
            const u16* kp  = kbase + (k0 + lm) * DD + quad * 8;
            s0 = __builtin_amdgcn_mfma_f32_16x16x32_bf16(qf0, ldb8(kp),       s0, 0,0,0);
            s0 = __builtin_amdgcn_mfma_f32_16x16x32_bf16(qf1, ldb8(kp + 32),  s0, 0,0,0);
            const u16* kp2 = kbase + (k0 + 16 + lm) * DD + quad * 8;
            s1 = __builtin_amdgcn_mfma_f32_16x16x32_bf16(qf0, ldb8(kp2),      s1, 0,0,0);
            s1 = __builtin_amdgcn_mfma_f32_16x16x32_bf16(qf1, ldb8(kp2 + 32), s1, 0,0,0);
        }
        // mask + scale; row max
        float cm[4], sc0[4], sc1[4];
        #pragma unroll
        for (int r = 0; r < 4; r++) {
            const int row = q0 + quad * 4 + r;
            sc0[r] = (k0 + lm      <= row) ? s0[r] * scale : -INFINITY;
            sc1[r] = (k0 + 16 + lm <= row) ? s1[r] * scale : -INFINITY;
            cm[r] = fmaxf(sc0[r], sc1[r]);
        }
        #pragma unroll
        for (int off = 8; off >= 1; off >>= 1) {
            #pragma unroll
            for (int r = 0; r < 4; r++) cm[r] = fmaxf(cm[r], __shfl_xor(cm[r], off));
        }
        // online softmax update
        float alpha[4], rs[4];
        #pragma unroll
        for (int r = 0; r < 4; r++) {
            const float mnew = fmaxf(mr[r], cm[r]);
            alpha[r] = __expf(mr[r] - mnew);
            mr[r] = mnew;
            const float e0 = __expf(sc0[r] - mnew);
            const float e1 = __expf(sc1[r] - mnew);
            rs[r] = e0 + e1;
            Plds[(quad * 4 + r) * 32 + lm]      = f2bf(e0);
            Plds[(quad * 4 + r) * 32 + 16 + lm] = f2bf(e1);
        }
        #pragma unroll
        for (int off = 8; off >= 1; off >>= 1) {
            #pragma unroll
            for (int r = 0; r < 4; r++) rs[r] += __shfl_xor(rs[r], off);
        }
        #pragma unroll
        for (int r = 0; r < 4; r++) lr[r] = lr[r] * alpha[r] + rs[r];
        __syncthreads();
        // P (C-layout) -> A-layout via LDS
        const bf16x8 pf = ldb8((const u16*)&Plds[lm * 32 + quad * 8]);
        // O = O*alpha + P V
        #pragma unroll
        for (int r = 0; r < 4; r++) { o0[r] *= alpha[r]; o1[r] *= alpha[r]; o2[r] *= alpha[r]; o3[r] *= alpha[r]; }
        const u16* vp = vbase + lm * SS + k0 + quad * 8;
        o0 = __builtin_amdgcn_mfma_f32_16x16x32_bf16(pf, ldb8(vp),           o0, 0,0,0);
        o1 = __builtin_amdgcn_mfma_f32_16x16x32_bf16(pf, ldb8(vp + 16 * SS), o1, 0,0,0);
        o2 = __builtin_amdgcn_mfma_f32_16x16x32_bf16(pf, ldb8(vp + 32 * SS), o2, 0,0,0);
        o3 = __builtin_amdgcn_mfma_f32_16x16x32_bf16(pf, ldb8(vp + 48 * SS), o3, 0,0,0);
        __syncthreads();
    }
    // epilogue: O/l -> Ob[b*S+q][h*D+d] bf16
    u16* obase = Ob + (b * SS + q0) * EE + h * DD;
    #pragma unroll
    for (int r = 0; r < 4; r++) {
        const float inv = 1.0f / lr[r];
        u16* op = obase + (quad * 4 + r) * EE;
        op[lm]      = f2bf(o0[r] * inv);
        op[16 + lm] = f2bf(o1[r] * inv);
        op[32 + lm] = f2bf(o2[r] * inv);
        op[48 + lm] = f2bf(o3[r] * inv);
    }
}

// ---------- 5. out-proj GEMM: [4096,1024] x [1024,1024] + bias -> fp32 ----------
__global__ __launch_bounds__(256) void gemm_out_kernel(
    const u16* __restrict__ A,   // O bf16 [4096][1024]
    const u16* __restrict__ BT,  // W_out^T bf16 [1024][1024]
    const float* __restrict__ bias,
    float* __restrict__ Out)
{
    const int K = EE;
    const int NT = EE / 16;      // 64
    const int lane = threadIdx.x & 63;
    const int wave = threadIdx.x >> 6;
    const int t = blockIdx.x * 4 + wave;
    const int tm = t / NT, tn = t % NT;
    const int lm = lane & 15, quad = lane >> 4;
    const u16* ap = A  + (tm * 16 + lm) * K + quad * 8;
    const u16* bp = BT + (tn * 16 + lm) * K + quad * 8;
    f32x4 acc = {0.f, 0.f, 0.f, 0.f};
    #pragma unroll 4
    for (int k0 = 0; k0 < K; k0 += 32)
        acc = __builtin_amdgcn_mfma_f32_16x16x32_bf16(ldb8(ap + k0), ldb8(bp + k0), acc, 0, 0, 0);
    const int n = tn * 16 + lm;
    const float bv = bias[n];
    #pragma unroll
    for (int r = 0; r < 4; r++) {
        const int m = tm * 16 + quad * 4 + r;
        Out[m * EE + n] = acc[r] + bv;
    }
}

// ---------- launch ----------
extern "C" void kernel_launch(void* const* d_in, const int* in_sizes, int n_in,
                              void* d_out, int out_size, void* d_ws, size_t ws_size,
                              hipStream_t stream)
{
    const float* x     = (const float*)d_in[0];
    const float* Wqkv  = (const float*)d_in[1];
    const float* bqkv  = (const float*)d_in[2];
    const float* Wout  = (const float*)d_in[3];
    const float* bout  = (const float*)d_in[4];
    float* out = (float*)d_out;

    // workspace layout (bytes)
    char* ws = (char*)d_ws;
    u16* xb    = (u16*)(ws + 0);          //  8 MB  x bf16 [4096][1024]
    u16* wqkvT = (u16*)(ws + 8388608);    //  6 MB  W_qkv^T bf16 [3072][1024]
    u16* woutT = (u16*)(ws + 14680064);   //  2 MB  W_out^T bf16 [1024][1024]
    u16* Qb    = (u16*)(ws + 16777216);   //  8 MB  [B,H,S,D]
    u16* Kb    = (u16*)(ws + 25165824);   //  8 MB  [B,H,S,D]
    u16* Vb    = (u16*)(ws + 33554432);   //  8 MB  [B,H,D,S]
    u16* Ob    = (u16*)(ws + 41943040);   //  8 MB  [B*S][E]
    if (ws_size < 50331648) return;       // need 48 MB

    conv_kernel<<<4096, 256, 0, stream>>>(x, xb, (BB * SS * EE) / 4);
    transpose_kernel<<<(EE / 32) * (3 * EE / 32), 256, 0, stream>>>(Wqkv, wqkvT, EE, 3 * EE);
    transpose_kernel<<<(EE / 32) * (EE / 32), 256, 0, stream>>>(Wout, woutT, EE, EE);
    gemm_qkv_kernel<<<(BB * SS / 16) * (3 * EE / 16) / 4, 256, 0, stream>>>(xb, wqkvT, bqkv, Qb, Kb, Vb);
    attn_kernel<<<BB * HH * (SS / 16), 64, 0, stream>>>(Qb, Kb, Vb, Ob);
    gemm_out_kernel<<<(BB * SS / 16) * (EE / 16) / 4, 256, 0, stream>>>(Ob, woutT, bout, out);
}

// Round 2
// 375.106 us; speedup vs baseline: 2.0508x; 2.0508x over previous
//
#include <hip/hip_runtime.h>

typedef unsigned short u16;
typedef __bf16  bf16x8 __attribute__((ext_vector_type(8)));
typedef float   f32x4  __attribute__((ext_vector_type(4)));
typedef unsigned int   u32x4 __attribute__((ext_vector_type(4)));
typedef unsigned short u16x4 __attribute__((ext_vector_type(4)));

#define BB 2
#define HH 16
#define DD 64
#define SS 2048
#define EE 1024

#define BM 128
#define BN 128
#define BK 32

// ---------- helpers ----------
static __device__ __forceinline__ u16 f2bf(float f) {
    unsigned int u = __float_as_uint(f);
    u += 0x7FFFu + ((u >> 16) & 1u);          // round-to-nearest-even
    return (u16)(u >> 16);
}

union BfCast { u32x4 u; bf16x8 b; };
static __device__ __forceinline__ bf16x8 ldb8(const u16* p) {
    BfCast x; x.u = *(const u32x4*)p; return x.b;
}

// async global->LDS, 16B per lane; LDS dest = wave-uniform base + lane*16
static __device__ __forceinline__ void gload16(const u16* g, u16* l) {
    __builtin_amdgcn_global_load_lds(
        (const __attribute__((address_space(1))) unsigned int*)g,
        (__attribute__((address_space(3))) unsigned int*)l, 16, 0, 0);
}

// ---------- 1. fp32 -> bf16 convert (x) ----------
__global__ __launch_bounds__(256) void conv_kernel(
    const float* __restrict__ in, u16* __restrict__ out, int n4)
{
    int i = blockIdx.x * blockDim.x + threadIdx.x;
    if (i < n4) {
        f32x4 v = ((const f32x4*)in)[i];
        u16x4 o;
        o[0] = f2bf(v[0]); o[1] = f2bf(v[1]); o[2] = f2bf(v[2]); o[3] = f2bf(v[3]);
        ((u16x4*)out)[i] = o;
    }
}

// ---------- 2. transpose + convert: in[R][C] fp32 -> out[C][R] bf16 ----------
__global__ __launch_bounds__(256) void transpose_kernel(
    const float* __restrict__ in, u16* __restrict__ out, int R, int C)
{
    __shared__ float tile[32][33];
    const int tx = threadIdx.x & 31;
    const int ty = threadIdx.x >> 5;          // 0..7
    const int ct = C >> 5;
    const int bc = blockIdx.x % ct;
    const int br = blockIdx.x / ct;
    const int c0 = bc * 32, r0 = br * 32;
    #pragma unroll
    for (int i = 0; i < 4; i++)
        tile[ty + i * 8][tx] = in[(r0 + ty + i * 8) * C + c0 + tx];
    __syncthreads();
    #pragma unroll
    for (int i = 0; i < 4; i++)
        out[(c0 + ty + i * 8) * R + r0 + tx] = f2bf(tile[tx][ty + i * 8]);
}

// ---------- 3. QKV GEMM (m97-style 128x128 tile): A[4096,1024] x BT[3072,1024]^T + bias
//             -> Q,K [B,H,S,D], V [B,H,D,S] ----------
__global__ __launch_bounds__(256) void gemm_qkv_kernel(
    const u16* __restrict__ A,   // x bf16 [4096][1024]
    const u16* __restrict__ BT,  // W_qkv^T bf16 [3072][1024]
    const float* __restrict__ bias,
    u16* __restrict__ Qb, u16* __restrict__ Kb, u16* __restrict__ Vb)
{
    __shared__ __align__(16) u16 As[BM * BK];   // [128][32] row-major, no pad (global_load_lds)
    __shared__ __align__(16) u16 Bs[BN * BK];
    const int K = EE;
    const int lane = threadIdx.x & 63;
    const int wave = threadIdx.x >> 6;
    const int nb = 3 * EE / BN;                 // 24
    const int tm = blockIdx.x / nb, tn = blockIdx.x % nb;
    const int lm = lane & 15, quad = lane >> 4;

    // staging: wave w covers rows w*32 .. w*32+31 in two 16-row chunks
    const int srow = wave * 32 + (lane >> 2);
    const int scol = (lane & 3) * 8;
    const u16* ag = A  + (tm * BM + srow) * K + scol;
    const u16* bg = BT + (tn * BN + srow) * K + scol;
    u16* al = As + (wave * 32) * BK;            // HW adds lane*16B
    u16* bl = Bs + (wave * 32) * BK;

    const int wy = wave >> 1, wx = wave & 1;    // 2x2 wave grid, 64x64 per wave
    f32x4 acc[4][4] = {};

    for (int k0 = 0; k0 < K; k0 += BK) {
        __syncthreads();                        // protect LDS from overwrite
        gload16(ag,          al);
        gload16(ag + 16 * K, al + 16 * BK);
        gload16(bg,          bl);
        gload16(bg + 16 * K, bl + 16 * BK);
        ag += BK; bg += BK;
        __syncthreads();                        // staged data visible
        bf16x8 af[4], bf[4];
        #pragma unroll
        for (int i = 0; i < 4; i++) {
            af[i] = ldb8(As + (wy * 64 + i * 16 + lm) * BK + quad * 8);
            bf[i] = ldb8(Bs + (wx * 64 + i * 16 + lm) * BK + quad * 8);
        }
        #pragma unroll
        for (int mi = 0; mi < 4; mi++)
            #pragma unroll
            for (int ni = 0; ni < 4; ni++)
                acc[mi][ni] = __builtin_amdgcn_mfma_f32_16x16x32_bf16(af[mi], bf[ni], acc[mi][ni], 0, 0, 0);
    }

    // epilogue: bias + scatter (which/h/d uniform per block per (ni,lm))
    const int gm0 = tm * BM + wy * 64;
    const int gn0 = tn * BN + wx * 64;
    #pragma unroll
    for (int ni = 0; ni < 4; ni++) {
        const int n = gn0 + ni * 16 + lm;
        const float bv = bias[n];
        const int which = n >> 10;              // 0=q 1=k 2=v (uniform per block)
        const int e = n & 1023;
        const int h = e >> 6, d = e & 63;
        #pragma unroll
        for (int mi = 0; mi < 4; mi++) {
            if (which == 2) {
                // V transposed: s runs over r -> contiguous, pack 8B store
                const int m0 = gm0 + mi * 16 + quad * 4;
                const int b = m0 >> 11, s = m0 & 2047;
                u16x4 pk;
                #pragma unroll
                for (int r = 0; r < 4; r++) pk[r] = f2bf(acc[mi][ni][r] + bv);
                *(u16x4*)&Vb[((b * HH + h) * DD + d) * SS + s] = pk;
            } else {
                #pragma unroll
                for (int r = 0; r < 4; r++) {
                    const int m = gm0 + mi * 16 + quad * 4 + r;
                    const int b = m >> 11, s = m & 2047;
                    const u16 val = f2bf(acc[mi][ni][r] + bv);
                    if (which == 0) Qb[((b * HH + h) * SS + s) * DD + d] = val;
                    else            Kb[((b * HH + h) * SS + s) * DD + d] = val;
                }
            }
        }
    }
}

// ---------- 4. causal flash attention: 1 wave per (b,h, 16-row q-tile) ----------
__global__ __launch_bounds__(64) void attn_kernel(
    const u16* __restrict__ Qb, const u16* __restrict__ Kb,
    const u16* __restrict__ Vb, u16* __restrict__ Ob)   // Ob: [B*S][E] bf16
{
    __shared__ __align__(16) u16 Plds[16 * 32];
    const int lane = threadIdx.x;
    const int lm = lane & 15, quad = lane >> 4;
    const int qt = blockIdx.x & (SS / 16 - 1);
    const int bh = blockIdx.x >> 7;            // B*H = 32
    const int q0 = qt * 16;
    const int b = bh >> 4, h = bh & 15;

    const u16* qbase = Qb + (bh * SS + q0) * DD;
    const bf16x8 qf0 = ldb8(qbase + lm * DD + quad * 8);
    const bf16x8 qf1 = ldb8(qbase + lm * DD + 32 + quad * 8);

    f32x4 o0 = {0,0,0,0}, o1 = {0,0,0,0}, o2 = {0,0,0,0}, o3 = {0,0,0,0};
    float mr[4] = {-INFINITY, -INFINITY, -INFINITY, -INFINITY};
    float lr[4] = {0.f, 0.f, 0.f, 0.f};

    const u16* kbase = Kb + bh * SS * DD;
    const u16* vbase = Vb + bh * DD * SS;
    const float scale = 0.125f;                // 1/sqrt(64)

    const int ktiles = (q0 >> 5) + 1;          // all tiles with k0 <= q0
    for (int kt = 0; kt < ktiles; ++kt) {
        const int k0 = kt * 32;
        f32x4 s0 = {0,0,0,0}, s1 = {0,0,0,0};
        {
            const u16* kp  = kbase + (k0 + lm) * DD + quad * 8;
            s0 = __builtin_amdgcn_mfma_f32_16x16x32_bf16(qf0, ldb8(kp),       s0, 0,0,0);
            s0 = __builtin_amdgcn_mfma_f32_16x16x32_bf16(qf1, ldb8(kp + 32),  s0, 0,0,0);
            const u16* kp2 = kbase + (k0 + 16 + lm) * DD + quad * 8;
            s1 = __builtin_amdgcn_mfma_f32_16x16x32_bf16(qf0, ldb8(kp2),      s1, 0,0,0);
            s1 = __builtin_amdgcn_mfma_f32_16x16x32_bf16(qf1, ldb8(kp2 + 32), s1, 0,0,0);
        }
        float cm[4], sc0[4], sc1[4];
        #pragma unroll
        for (int r = 0; r < 4; r++) {
            const int row = q0 + quad * 4 + r;
            sc0[r] = (k0 + lm      <= row) ? s0[r] * scale : -INFINITY;
            sc1[r] = (k0 + 16 + lm <= row) ? s1[r] * scale : -INFINITY;
            cm[r] = fmaxf(sc0[r], sc1[r]);
        }
        #pragma unroll
        for (int off = 8; off >= 1; off >>= 1) {
            #pragma unroll
            for (int r = 0; r < 4; r++) cm[r] = fmaxf(cm[r], __shfl_xor(cm[r], off));
        }
        float alpha[4], rs[4];
        #pragma unroll
        for (int r = 0; r < 4; r++) {
            const float mnew = fmaxf(mr[r], cm[r]);
            alpha[r] = __expf(mr[r] - mnew);
            mr[r] = mnew;
            const float e0 = __expf(sc0[r] - mnew);
            const float e1 = __expf(sc1[r] - mnew);
            rs[r] = e0 + e1;
            Plds[(quad * 4 + r) * 32 + lm]      = f2bf(e0);
            Plds[(quad * 4 + r) * 32 + 16 + lm] = f2bf(e1);
        }
        #pragma unroll
        for (int off = 8; off >= 1; off >>= 1) {
            #pragma unroll
            for (int r = 0; r < 4; r++) rs[r] += __shfl_xor(rs[r], off);
        }
        #pragma unroll
        for (int r = 0; r < 4; r++) lr[r] = lr[r] * alpha[r] + rs[r];
        __syncthreads();
        const bf16x8 pf = ldb8((const u16*)&Plds[lm * 32 + quad * 8]);
        #pragma unroll
        for (int r = 0; r < 4; r++) { o0[r] *= alpha[r]; o1[r] *= alpha[r]; o2[r] *= alpha[r]; o3[r] *= alpha[r]; }
        const u16* vp = vbase + lm * SS + k0 + quad * 8;
        o0 = __builtin_amdgcn_mfma_f32_16x16x32_bf16(pf, ldb8(vp),           o0, 0,0,0);
        o1 = __builtin_amdgcn_mfma_f32_16x16x32_bf16(pf, ldb8(vp + 16 * SS), o1, 0,0,0);
        o2 = __builtin_amdgcn_mfma_f32_16x16x32_bf16(pf, ldb8(vp + 32 * SS), o2, 0,0,0);
        o3 = __builtin_amdgcn_mfma_f32_16x16x32_bf16(pf, ldb8(vp + 48 * SS), o3, 0,0,0);
        __syncthreads();
    }
    u16* obase = Ob + (b * SS + q0) * EE + h * DD;
    #pragma unroll
    for (int r = 0; r < 4; r++) {
        const float inv = 1.0f / lr[r];
        u16* op = obase + (quad * 4 + r) * EE;
        op[lm]      = f2bf(o0[r] * inv);
        op[16 + lm] = f2bf(o1[r] * inv);
        op[32 + lm] = f2bf(o2[r] * inv);
        op[48 + lm] = f2bf(o3[r] * inv);
    }
}

// ---------- 5. out-proj GEMM (m97-style): [4096,1024] x [1024,1024] + bias -> fp32 ----------
__global__ __launch_bounds__(256) void gemm_out_kernel(
    const u16* __restrict__ A,   // O bf16 [4096][1024]
    const u16* __restrict__ BT,  // W_out^T bf16 [1024][1024]
    const float* __restrict__ bias,
    float* __restrict__ Out)
{
    __shared__ __align__(16) u16 As[BM * BK];
    __shared__ __align__(16) u16 Bs[BN * BK];
    const int K = EE;
    const int lane = threadIdx.x & 63;
    const int wave = threadIdx.x >> 6;
    const int nb = EE / BN;                     // 8
    const int tm = blockIdx.x / nb, tn = blockIdx.x % nb;
    const int lm = lane & 15, quad = lane >> 4;

    const int srow = wave * 32 + (lane >> 2);
    const int scol = (lane & 3) * 8;
    const u16* ag = A  + (tm * BM + srow) * K + scol;
    const u16* bg = BT + (tn * BN + srow) * K + scol;
    u16* al = As + (wave * 32) * BK;
    u16* bl = Bs + (wave * 32) * BK;

    const int wy = wave >> 1, wx = wave & 1;
    f32x4 acc[4][4] = {};

    for (int k0 = 0; k0 < K; k0 += BK) {
        __syncthreads();
        gload16(ag,          al);
        gload16(ag + 16 * K, al + 16 * BK);
        gload16(bg,          bl);
        gload16(bg + 16 * K, bl + 16 * BK);
        ag += BK; bg += BK;
        __syncthreads();
        bf16x8 af[4], bf[4];
        #pragma unroll
        for (int i = 0; i < 4; i++) {
            af[i] = ldb8(As + (wy * 64 + i * 16 + lm) * BK + quad * 8);
            bf[i] = ldb8(Bs + (wx * 64 + i * 16 + lm) * BK + quad * 8);
        }
        #pragma unroll
        for (int mi = 0; mi < 4; mi++)
            #pragma unroll
            for (int ni = 0; ni < 4; ni++)
                acc[mi][ni] = __builtin_amdgcn_mfma_f32_16x16x32_bf16(af[mi], bf[ni], acc[mi][ni], 0, 0, 0);
    }

    const int gm0 = tm * BM + wy * 64;
    const int gn0 = tn * BN + wx * 64;
    #pragma unroll
    for (int ni = 0; ni < 4; ni++) {
        const int n = gn0 + ni * 16 + lm;
        const float bv = bias[n];
        #pragma unroll
        for (int mi = 0; mi < 4; mi++)
            #pragma unroll
            for (int r = 0; r < 4; r++)
                Out[(gm0 + mi * 16 + quad * 4 + r) * EE + n] = acc[mi][ni][r] + bv;
    }
}

// ---------- launch ----------
extern "C" void kernel_launch(void* const* d_in, const int* in_sizes, int n_in,
                              void* d_out, int out_size, void* d_ws, size_t ws_size,
                              hipStream_t stream)
{
    const float* x     = (const float*)d_in[0];
    const float* Wqkv  = (const float*)d_in[1];
    const float* bqkv  = (const float*)d_in[2];
    const float* Wout  = (const float*)d_in[3];
    const float* bout  = (const float*)d_in[4];
    float* out = (float*)d_out;

    char* ws = (char*)d_ws;
    u16* xb    = (u16*)(ws + 0);          //  8 MB  x bf16 [4096][1024]
    u16* wqkvT = (u16*)(ws + 8388608);    //  6 MB  W_qkv^T bf16 [3072][1024]
    u16* woutT = (u16*)(ws + 14680064);   //  2 MB  W_out^T bf16 [1024][1024]
    u16* Qb    = (u16*)(ws + 16777216);   //  8 MB  [B,H,S,D]
    u16* Kb    = (u16*)(ws + 25165824);   //  8 MB  [B,H,S,D]
    u16* Vb    = (u16*)(ws + 33554432);   //  8 MB  [B,H,D,S]
    u16* Ob    = (u16*)(ws + 41943040);   //  8 MB  [B*S][E]
    if (ws_size < 50331648) return;       // need 48 MB

    conv_kernel<<<4096, 256, 0, stream>>>(x, xb, (BB * SS * EE) / 4);
    transpose_kernel<<<(EE / 32) * (3 * EE / 32), 256, 0, stream>>>(Wqkv, wqkvT, EE, 3 * EE);
    transpose_kernel<<<(EE / 32) * (EE / 32), 256, 0, stream>>>(Wout, woutT, EE, EE);
    gemm_qkv_kernel<<<(BB * SS / BM) * (3 * EE / BN), 256, 0, stream>>>(xb, wqkvT, bqkv, Qb, Kb, Vb);
    attn_kernel<<<BB * HH * (SS / 16), 64, 0, stream>>>(Qb, Kb, Vb, Ob);
    gemm_out_kernel<<<(BB * SS / BM) * (EE / BN), 256, 0, stream>>>(Ob, woutT, bout, out);
}

// Round 4
// 212.471 us; speedup vs baseline: 3.6206x; 1.7654x over previous
//
#include <hip/hip_runtime.h>

typedef unsigned short u16;
typedef __bf16  bf16x8 __attribute__((ext_vector_type(8)));
typedef float   f32x4  __attribute__((ext_vector_type(4)));
typedef unsigned int   u32x4 __attribute__((ext_vector_type(4)));
typedef unsigned short u16x4 __attribute__((ext_vector_type(4)));

#define BB 2
#define HH 16
#define DD 64
#define SS 2048
#define EE 1024

#define BM 128
#define BN 128
#define BK 32

// scale(1/8) * log2(e) folded into Q at the QKV epilogue -> scores are exp2-ready
#define QSCALE 0.1803368801111244f

// ---------- helpers ----------
static __device__ __forceinline__ u16 f2bf(float f) {
    unsigned int u = __float_as_uint(f);
    u += 0x7FFFu + ((u >> 16) & 1u);          // round-to-nearest-even
    return (u16)(u >> 16);
}

union BfCast { u32x4 u; bf16x8 b; };
static __device__ __forceinline__ bf16x8 ldb8(const u16* p) {
    BfCast x; x.u = *(const u32x4*)p; return x.b;
}

// async global->LDS, 16B per lane; GLOBAL addr is PER-LANE, LDS dest = wave-uniform base + lane*16
static __device__ __forceinline__ void gload16(const u16* g, u16* l) {
    __builtin_amdgcn_global_load_lds(
        (const __attribute__((address_space(1))) unsigned int*)g,
        (__attribute__((address_space(3))) unsigned int*)l, 16, 0, 0);
}

// fragment-ordered global layouts (per bh plane of 131072 u16 = 256 KB):
// K as QK^T B-operand: blocks of 1KB = (s-group-of-16)*2 + (d>>5); within: lane=((d>>3)&3)*16+(s&15), j=d&7
static __device__ __forceinline__ int kidx(int s, int d) {
    return (((s >> 4) * 2 + (d >> 5)) * 512) + ((((d >> 3) & 3) * 16 + (s & 15)) * 8) + (d & 7);
}
// V as PV B-operand: blocks of 1KB = (key>>5)*4 + (d>>4); within: lane=((key>>3)&3)*16+(d&15), j=key&7
static __device__ __forceinline__ int vidx(int key, int d) {
    return (((key >> 5) * 4 + (d >> 4)) * 512) + ((((key >> 3) & 3) * 16 + (d & 15)) * 8) + (key & 7);
}

// ---------- 1. fp32 -> bf16 convert (x) ----------
__global__ __launch_bounds__(256) void conv_kernel(
    const float* __restrict__ in, u16* __restrict__ out, int n4)
{
    int i = blockIdx.x * blockDim.x + threadIdx.x;
    if (i < n4) {
        f32x4 v = ((const f32x4*)in)[i];
        u16x4 o;
        o[0] = f2bf(v[0]); o[1] = f2bf(v[1]); o[2] = f2bf(v[2]); o[3] = f2bf(v[3]);
        ((u16x4*)out)[i] = o;
    }
}

// ---------- 2. transpose + convert: in[R][C] fp32 -> out[C][R] bf16 ----------
__global__ __launch_bounds__(256) void transpose_kernel(
    const float* __restrict__ in, u16* __restrict__ out, int R, int C)
{
    __shared__ float tile[32][33];
    const int tx = threadIdx.x & 31;
    const int ty = threadIdx.x >> 5;          // 0..7
    const int ct = C >> 5;
    const int bc = blockIdx.x % ct;
    const int br = blockIdx.x / ct;
    const int c0 = bc * 32, r0 = br * 32;
    #pragma unroll
    for (int i = 0; i < 4; i++)
        tile[ty + i * 8][tx] = in[(r0 + ty + i * 8) * C + c0 + tx];
    __syncthreads();
    #pragma unroll
    for (int i = 0; i < 4; i++)
        out[(c0 + ty + i * 8) * R + r0 + tx] = f2bf(tile[tx][ty + i * 8]);
}

// ---------- 3. QKV GEMM (m97-style 128x128 tile) -> Q scaled [B,H,S,D]; K,V fragment-ordered ----------
__global__ __launch_bounds__(256) void gemm_qkv_kernel(
    const u16* __restrict__ A,   // x bf16 [4096][1024]
    const u16* __restrict__ BT,  // W_qkv^T bf16 [3072][1024]
    const float* __restrict__ bias,
    u16* __restrict__ Qb, u16* __restrict__ Kb, u16* __restrict__ Vb)
{
    __shared__ __align__(16) u16 As[BM * BK];   // [128][32] row-major, no pad (global_load_lds)
    __shared__ __align__(16) u16 Bs[BN * BK];
    const int K = EE;
    const int lane = threadIdx.x & 63;
    const int wave = threadIdx.x >> 6;
    const int nb = 3 * EE / BN;                 // 24
    const int tm = blockIdx.x / nb, tn = blockIdx.x % nb;
    const int lm = lane & 15, quad = lane >> 4;

    const int srow = wave * 32 + (lane >> 2);
    const int scol = (lane & 3) * 8;
    const u16* ag = A  + (tm * BM + srow) * K + scol;
    const u16* bg = BT + (tn * BN + srow) * K + scol;
    u16* al = As + (wave * 32) * BK;            // HW adds lane*16B
    u16* bl = Bs + (wave * 32) * BK;

    const int wy = wave >> 1, wx = wave & 1;    // 2x2 wave grid, 64x64 per wave
    f32x4 acc[4][4] = {};

    for (int k0 = 0; k0 < K; k0 += BK) {
        __syncthreads();
        gload16(ag,          al);
        gload16(ag + 16 * K, al + 16 * BK);
        gload16(bg,          bl);
        gload16(bg + 16 * K, bl + 16 * BK);
        ag += BK; bg += BK;
        __syncthreads();
        bf16x8 af[4], bf[4];
        #pragma unroll
        for (int i = 0; i < 4; i++) {
            af[i] = ldb8(As + (wy * 64 + i * 16 + lm) * BK + quad * 8);
            bf[i] = ldb8(Bs + (wx * 64 + i * 16 + lm) * BK + quad * 8);
        }
        #pragma unroll
        for (int mi = 0; mi < 4; mi++)
            #pragma unroll
            for (int ni = 0; ni < 4; ni++)
                acc[mi][ni] = __builtin_amdgcn_mfma_f32_16x16x32_bf16(af[mi], bf[ni], acc[mi][ni], 0, 0, 0);
    }

    const int gm0 = tm * BM + wy * 64;
    const int gn0 = tn * BN + wx * 64;
    #pragma unroll
    for (int ni = 0; ni < 4; ni++) {
        const int n = gn0 + ni * 16 + lm;
        const float bv = bias[n];
        const int which = n >> 10;              // 0=q 1=k 2=v (uniform per block)
        const int e = n & 1023;
        const int h = e >> 6, d = e & 63;
        #pragma unroll
        for (int mi = 0; mi < 4; mi++) {
            if (which == 2) {
                const int m0 = gm0 + mi * 16 + quad * 4;
                const int b = m0 >> 11, key0 = m0 & 2047;
                u16x4 pk;
                #pragma unroll
                for (int r = 0; r < 4; r++) pk[r] = f2bf(acc[mi][ni][r] + bv);
                // vidx(key0+r,d) = vidx(key0,d)+r (key0%4==0 -> j-group stays)
                *(u16x4*)&Vb[(b * HH + h) * 131072 + vidx(key0, d)] = pk;
            } else if (which == 1) {
                #pragma unroll
                for (int r = 0; r < 4; r++) {
                    const int m = gm0 + mi * 16 + quad * 4 + r;
                    const int b = m >> 11, s = m & 2047;
                    Kb[(b * HH + h) * 131072 + kidx(s, d)] = f2bf(acc[mi][ni][r] + bv);
                }
            } else {
                #pragma unroll
                for (int r = 0; r < 4; r++) {
                    const int m = gm0 + mi * 16 + quad * 4 + r;
                    const int b = m >> 11, s = m & 2047;
                    Qb[((b * HH + h) * SS + s) * DD + d] = f2bf((acc[mi][ni][r] + bv) * QSCALE);
                }
            }
        }
    }
}

// ---------- 4. causal flash attention: 4 waves / 64 q-rows per block, 64-key LDS-staged tiles ----------
__global__ __launch_bounds__(256) void attn_kernel(
    const u16* __restrict__ Qb, const u16* __restrict__ Kb,
    const u16* __restrict__ Vb, u16* __restrict__ Ob)   // Ob: [B*S][E] bf16
{
    __shared__ __align__(16) u16 Ks[4096];          // 8 KB: 8 frag-blocks of 1KB (g*2+h)
    __shared__ __align__(16) u16 Vs[4096];          // 8 KB: 8 frag-blocks of 1KB (kg*4+dg)
    __shared__ __align__(16) u16 Plds[4 * 16 * 72]; // per-wave P, row-padded to 72
    const int tid = threadIdx.x;
    const int lane = tid & 63, wave = tid >> 6;
    const int lm = lane & 15, quad = lane >> 4;
    const int bh = blockIdx.x & 31;
    const int qt = 31 - (blockIdx.x >> 5);          // heavy q-tiles dispatch first
    const int q0 = qt * 64;
    const int b = bh >> 4, h = bh & 15;

    // Q A-fragments for this wave's 16 rows (scores come out pre-scaled by QSCALE)
    const u16* qbase = Qb + (bh * SS + q0 + wave * 16) * DD;
    const bf16x8 qf0 = ldb8(qbase + lm * DD + quad * 8);
    const bf16x8 qf1 = ldb8(qbase + lm * DD + 32 + quad * 8);

    const u16* ktile = Kb + bh * 131072;            // + kt*4096 per 64-key tile
    const u16* vtile = Vb + bh * 131072;
    u16* Pw = Plds + wave * (16 * 72);

    BfCast oc; oc.u = (u32x4){0x3F803F80u, 0x3F803F80u, 0x3F803F80u, 0x3F803F80u};
    const bf16x8 ones = oc.b;

    f32x4 oacc[4] = {};                             // O[row=quad*4+r][d = dg*16+lm]
    f32x4 lacc = {0.f, 0.f, 0.f, 0.f};              // row sums (via ones-MFMA)
    float mr[4] = {-INFINITY, -INFINITY, -INFINITY, -INFINITY};

    for (int kt = 0; kt <= qt; ++kt) {
        __syncthreads();                            // LDS safe to overwrite
        {
            // PER-LANE global source (+lane*8 u16 = lane*16B); wave-uniform LDS base
            const u16* ks = ktile + kt * 4096 + wave * 512 + lane * 8;
            const u16* vs = vtile + kt * 4096 + wave * 512 + lane * 8;
            gload16(ks,        Ks + wave * 512);
            gload16(ks + 2048, Ks + 2048 + wave * 512);
            gload16(vs,        Vs + wave * 512);
            gload16(vs + 2048, Vs + 2048 + wave * 512);
        }
        __syncthreads();                            // staged data visible

        // S = Q K^T  (4 key groups of 16, D=64 as two 32-contractions)
        f32x4 s[4];
        #pragma unroll
        for (int g = 0; g < 4; g++) {
            f32x4 z = {0.f, 0.f, 0.f, 0.f};
            z = __builtin_amdgcn_mfma_f32_16x16x32_bf16(qf0, ldb8(&Ks[(g * 2) * 512 + lane * 8]), z, 0, 0, 0);
            s[g] = __builtin_amdgcn_mfma_f32_16x16x32_bf16(qf1, ldb8(&Ks[(g * 2 + 1) * 512 + lane * 8]), z, 0, 0, 0);
        }
        if (kt == qt) {                             // diagonal tile: causal mask
            const int limit = wave * 16 + quad * 4;
            #pragma unroll
            for (int g = 0; g < 4; g++)
                #pragma unroll
                for (int r = 0; r < 4; r++)
                    if (g * 16 + lm > limit + r) s[g][r] = -INFINITY;
        }
        // row max (over 4 in-lane groups, then 16 lanes of lm)
        float cm[4];
        #pragma unroll
        for (int r = 0; r < 4; r++)
            cm[r] = fmaxf(fmaxf(s[0][r], s[1][r]), fmaxf(s[2][r], s[3][r]));
        #pragma unroll
        for (int off = 8; off >= 1; off >>= 1)
            #pragma unroll
            for (int r = 0; r < 4; r++) cm[r] = fmaxf(cm[r], __shfl_xor(cm[r], off));
        float alpha[4];
        #pragma unroll
        for (int r = 0; r < 4; r++) {
            const float mnew = fmaxf(mr[r], cm[r]);
            alpha[r] = __builtin_amdgcn_exp2f(mr[r] - mnew);
            mr[r] = mnew;
        }
        // P = exp2(S - m) -> per-wave LDS (C-layout -> A-layout transform)
        #pragma unroll
        for (int g = 0; g < 4; g++)
            #pragma unroll
            for (int r = 0; r < 4; r++)
                Pw[(quad * 4 + r) * 72 + g * 16 + lm] = f2bf(__builtin_amdgcn_exp2f(s[g][r] - mr[r]));
        const bf16x8 pf0 = ldb8(&Pw[lm * 72 + quad * 8]);
        const bf16x8 pf1 = ldb8(&Pw[lm * 72 + 32 + quad * 8]);
        // l = l*alpha + rowsum(P)  (ones-MFMA replaces shuffle-tree)
        #pragma unroll
        for (int r = 0; r < 4; r++) lacc[r] *= alpha[r];
        lacc = __builtin_amdgcn_mfma_f32_16x16x32_bf16(pf0, ones, lacc, 0, 0, 0);
        lacc = __builtin_amdgcn_mfma_f32_16x16x32_bf16(pf1, ones, lacc, 0, 0, 0);
        // O = O*alpha + P V
        #pragma unroll
        for (int dg = 0; dg < 4; dg++)
            #pragma unroll
            for (int r = 0; r < 4; r++) oacc[dg][r] *= alpha[r];
        #pragma unroll
        for (int dg = 0; dg < 4; dg++) {
            oacc[dg] = __builtin_amdgcn_mfma_f32_16x16x32_bf16(pf0, ldb8(&Vs[dg * 512 + lane * 8]), oacc[dg], 0, 0, 0);
            oacc[dg] = __builtin_amdgcn_mfma_f32_16x16x32_bf16(pf1, ldb8(&Vs[(4 + dg) * 512 + lane * 8]), oacc[dg], 0, 0, 0);
        }
    }
    // epilogue: O/l -> Ob[b*S+q][h*D+d] bf16
    u16* obase = Ob + (b * SS + q0 + wave * 16) * EE + h * DD;
    #pragma unroll
    for (int r = 0; r < 4; r++) {
        const float inv = 1.0f / lacc[r];
        u16* op = obase + (quad * 4 + r) * EE;
        #pragma unroll
        for (int dg = 0; dg < 4; dg++)
            op[dg * 16 + lm] = f2bf(oacc[dg][r] * inv);
    }
}

// ---------- 5. out-proj GEMM (m97-style): [4096,1024] x [1024,1024] + bias -> fp32 ----------
__global__ __launch_bounds__(256) void gemm_out_kernel(
    const u16* __restrict__ A,   // O bf16 [4096][1024]
    const u16* __restrict__ BT,  // W_out^T bf16 [1024][1024]
    const float* __restrict__ bias,
    float* __restrict__ Out)
{
    __shared__ __align__(16) u16 As[BM * BK];
    __shared__ __align__(16) u16 Bs[BN * BK];
    const int K = EE;
    const int lane = threadIdx.x & 63;
    const int wave = threadIdx.x >> 6;
    const int nb = EE / BN;                     // 8
    const int tm = blockIdx.x / nb, tn = blockIdx.x % nb;
    const int lm = lane & 15, quad = lane >> 4;

    const int srow = wave * 32 + (lane >> 2);
    const int scol = (lane & 3) * 8;
    const u16* ag = A  + (tm * BM + srow) * K + scol;
    const u16* bg = BT + (tn * BN + srow) * K + scol;
    u16* al = As + (wave * 32) * BK;
    u16* bl = Bs + (wave * 32) * BK;

    const int wy = wave >> 1, wx = wave & 1;
    f32x4 acc[4][4] = {};

    for (int k0 = 0; k0 < K; k0 += BK) {
        __syncthreads();
        gload16(ag,          al);
        gload16(ag + 16 * K, al + 16 * BK);
        gload16(bg,          bl);
        gload16(bg + 16 * K, bl + 16 * BK);
        ag += BK; bg += BK;
        __syncthreads();
        bf16x8 af[4], bf[4];
        #pragma unroll
        for (int i = 0; i < 4; i++) {
            af[i] = ldb8(As + (wy * 64 + i * 16 + lm) * BK + quad * 8);
            bf[i] = ldb8(Bs + (wx * 64 + i * 16 + lm) * BK + quad * 8);
        }
        #pragma unroll
        for (int mi = 0; mi < 4; mi++)
            #pragma unroll
            for (int ni = 0; ni < 4; ni++)
                acc[mi][ni] = __builtin_amdgcn_mfma_f32_16x16x32_bf16(af[mi], bf[ni], acc[mi][ni], 0, 0, 0);
    }

    const int gm0 = tm * BM + wy * 64;
    const int gn0 = tn * BN + wx * 64;
    #pragma unroll
    for (int ni = 0; ni < 4; ni++) {
        const int n = gn0 + ni * 16 + lm;
        const float bv = bias[n];
        #pragma unroll
        for (int mi = 0; mi < 4; mi++)
            #pragma unroll
            for (int r = 0; r < 4; r++)
                Out[(gm0 + mi * 16 + quad * 4 + r) * EE + n] = acc[mi][ni][r] + bv;
    }
}

// ---------- launch ----------
extern "C" void kernel_launch(void* const* d_in, const int* in_sizes, int n_in,
                              void* d_out, int out_size, void* d_ws, size_t ws_size,
                              hipStream_t stream)
{
    const float* x     = (const float*)d_in[0];
    const float* Wqkv  = (const float*)d_in[1];
    const float* bqkv  = (const float*)d_in[2];
    const float* Wout  = (const float*)d_in[3];
    const float* bout  = (const float*)d_in[4];
    float* out = (float*)d_out;

    char* ws = (char*)d_ws;
    u16* xb    = (u16*)(ws + 0);          //  8 MB  x bf16 [4096][1024]
    u16* wqkvT = (u16*)(ws + 8388608);    //  6 MB  W_qkv^T bf16 [3072][1024]
    u16* woutT = (u16*)(ws + 14680064);   //  2 MB  W_out^T bf16 [1024][1024]
    u16* Qb    = (u16*)(ws + 16777216);   //  8 MB  [B,H,S,D] (pre-scaled)
    u16* Kb    = (u16*)(ws + 25165824);   //  8 MB  frag-ordered
    u16* Vb    = (u16*)(ws + 33554432);   //  8 MB  frag-ordered
    u16* Ob    = (u16*)(ws + 41943040);   //  8 MB  [B*S][E]
    if (ws_size < 50331648) return;       // need 48 MB

    conv_kernel<<<4096, 256, 0, stream>>>(x, xb, (BB * SS * EE) / 4);
    transpose_kernel<<<(EE / 32) * (3 * EE / 32), 256, 0, stream>>>(Wqkv, wqkvT, EE, 3 * EE);
    transpose_kernel<<<(EE / 32) * (EE / 32), 256, 0, stream>>>(Wout, woutT, EE, EE);
    gemm_qkv_kernel<<<(BB * SS / BM) * (3 * EE / BN), 256, 0, stream>>>(xb, wqkvT, bqkv, Qb, Kb, Vb);
    attn_kernel<<<BB * HH * (SS / 64), 256, 0, stream>>>(Qb, Kb, Vb, Ob);
    gemm_out_kernel<<<(BB * SS / BM) * (EE / BN), 256, 0, stream>>>(Ob, woutT, bout, out);
}

// Round 5
// 205.013 us; speedup vs baseline: 3.7523x; 1.0364x over previous
//
#include <hip/hip_runtime.h>

typedef unsigned short u16;
typedef __bf16  bf16x8 __attribute__((ext_vector_type(8)));
typedef float   f32x4  __attribute__((ext_vector_type(4)));
typedef unsigned int   u32x4 __attribute__((ext_vector_type(4)));
typedef unsigned short u16x4 __attribute__((ext_vector_type(4)));

#define BB 2
#define HH 16
#define DD 64
#define SS 2048
#define EE 1024

#define BM 128
#define BN 128
#define BK 64            // two 32-col sub-buffers per operand, one barrier pair per 64-K

// scale(1/8) * log2(e) folded into Q at the QKV epilogue -> scores are exp2-ready
#define QSCALE 0.1803368801111244f

// ---------- helpers ----------
static __device__ __forceinline__ u16 f2bf(float f) {
    unsigned int u = __float_as_uint(f);
    u += 0x7FFFu + ((u >> 16) & 1u);          // round-to-nearest-even
    return (u16)(u >> 16);
}

union BfCast { u32x4 u; bf16x8 b; };
static __device__ __forceinline__ bf16x8 ldb8(const u16* p) {
    BfCast x; x.u = *(const u32x4*)p; return x.b;
}

// async global->LDS, 16B per lane; GLOBAL addr is PER-LANE, LDS dest = wave-uniform base + lane*16
static __device__ __forceinline__ void gload16(const u16* g, u16* l) {
    __builtin_amdgcn_global_load_lds(
        (const __attribute__((address_space(1))) unsigned int*)g,
        (__attribute__((address_space(3))) unsigned int*)l, 16, 0, 0);
}

// fragment-ordered global layouts (per bh plane of 131072 u16 = 256 KB):
// K as QK^T B-operand: blocks of 1KB = (s-group-of-16)*2 + (d>>5); within: lane=((d>>3)&3)*16+(s&15), j=d&7
static __device__ __forceinline__ int kidx(int s, int d) {
    return (((s >> 4) * 2 + (d >> 5)) * 512) + ((((d >> 3) & 3) * 16 + (s & 15)) * 8) + (d & 7);
}
// V as PV B-operand: blocks of 1KB = (key>>5)*4 + (d>>4); within: lane=((key>>3)&3)*16+(d&15), j=key&7
static __device__ __forceinline__ int vidx(int key, int d) {
    return (((key >> 5) * 4 + (d >> 4)) * 512) + ((((key >> 3) & 3) * 16 + (d & 15)) * 8) + (key & 7);
}

// ---------- 1. fp32 -> bf16 convert (x) ----------
__global__ __launch_bounds__(256) void conv_kernel(
    const float* __restrict__ in, u16* __restrict__ out, int n4)
{
    int i = blockIdx.x * blockDim.x + threadIdx.x;
    if (i < n4) {
        f32x4 v = ((const f32x4*)in)[i];
        u16x4 o;
        o[0] = f2bf(v[0]); o[1] = f2bf(v[1]); o[2] = f2bf(v[2]); o[3] = f2bf(v[3]);
        ((u16x4*)out)[i] = o;
    }
}

// ---------- 2. transpose + convert: in[R][C] fp32 -> out[C][R] bf16 ----------
__global__ __launch_bounds__(256) void transpose_kernel(
    const float* __restrict__ in, u16* __restrict__ out, int R, int C)
{
    __shared__ float tile[32][33];
    const int tx = threadIdx.x & 31;
    const int ty = threadIdx.x >> 5;          // 0..7
    const int ct = C >> 5;
    const int bc = blockIdx.x % ct;
    const int br = blockIdx.x / ct;
    const int c0 = bc * 32, r0 = br * 32;
    #pragma unroll
    for (int i = 0; i < 4; i++)
        tile[ty + i * 8][tx] = in[(r0 + ty + i * 8) * C + c0 + tx];
    __syncthreads();
    #pragma unroll
    for (int i = 0; i < 4; i++)
        out[(c0 + ty + i * 8) * R + r0 + tx] = f2bf(tile[tx][ty + i * 8]);
}

// ---------- 3. QKV GEMM (128x128 tile, BK=64) -> Q scaled [B,H,S,D]; K,V fragment-ordered ----------
__global__ __launch_bounds__(256) void gemm_qkv_kernel(
    const u16* __restrict__ A,   // x bf16 [4096][1024]
    const u16* __restrict__ BT,  // W_qkv^T bf16 [3072][1024]
    const float* __restrict__ bias,
    u16* __restrict__ Qb, u16* __restrict__ Kb, u16* __restrict__ Vb)
{
    __shared__ __align__(16) u16 As[2 * BM * 32];   // two [128][32] sub-buffers (k 0..31 | 32..63)
    __shared__ __align__(16) u16 Bs[2 * BN * 32];
    const int K = EE;
    const int lane = threadIdx.x & 63;
    const int wave = threadIdx.x >> 6;
    const int nb = 3 * EE / BN;                 // 24
    const int tm = blockIdx.x / nb, tn = blockIdx.x % nb;
    const int lm = lane & 15, quad = lane >> 4;

    // staging: lane covers row (lane>>2), col-chunk (lane&3)*8 within a 16-row slab
    const int srow = wave * 32 + (lane >> 2);
    const int scol = (lane & 3) * 8;
    const u16* ag = A  + (tm * BM + srow) * K + scol;
    const u16* bg = BT + (tn * BN + srow) * K + scol;
    u16* al = As + (wave * 32) * 32;            // HW adds lane*16B
    u16* bl = Bs + (wave * 32) * 32;

    const int wy = wave >> 1, wx = wave & 1;    // 2x2 wave grid, 64x64 per wave
    f32x4 acc[4][4] = {};

    for (int k0 = 0; k0 < K; k0 += BK) {
        __syncthreads();                        // LDS safe to overwrite
        gload16(ag,               al);
        gload16(ag + 16 * K,      al + 512);
        gload16(ag + 32,          al + 4096);
        gload16(ag + 32 + 16 * K, al + 4096 + 512);
        gload16(bg,               bl);
        gload16(bg + 16 * K,      bl + 512);
        gload16(bg + 32,          bl + 4096);
        gload16(bg + 32 + 16 * K, bl + 4096 + 512);
        ag += BK; bg += BK;
        __syncthreads();                        // staged data visible
        #pragma unroll
        for (int half = 0; half < 2; ++half) {
            const u16* Ah = As + half * 4096;
            const u16* Bh = Bs + half * 4096;
            bf16x8 af[4], bf[4];
            #pragma unroll
            for (int i = 0; i < 4; i++) {
                af[i] = ldb8(Ah + (wy * 64 + i * 16 + lm) * 32 + quad * 8);
                bf[i] = ldb8(Bh + (wx * 64 + i * 16 + lm) * 32 + quad * 8);
            }
            #pragma unroll
            for (int mi = 0; mi < 4; mi++)
                #pragma unroll
                for (int ni = 0; ni < 4; ni++)
                    acc[mi][ni] = __builtin_amdgcn_mfma_f32_16x16x32_bf16(af[mi], bf[ni], acc[mi][ni], 0, 0, 0);
        }
    }

    const int gm0 = tm * BM + wy * 64;
    const int gn0 = tn * BN + wx * 64;
    #pragma unroll
    for (int ni = 0; ni < 4; ni++) {
        const int n = gn0 + ni * 16 + lm;
        const float bv = bias[n];
        const int which = n >> 10;              // 0=q 1=k 2=v (uniform per block)
        const int e = n & 1023;
        const int h = e >> 6, d = e & 63;
        #pragma unroll
        for (int mi = 0; mi < 4; mi++) {
            if (which == 2) {
                const int m0 = gm0 + mi * 16 + quad * 4;
                const int b = m0 >> 11, key0 = m0 & 2047;
                u16x4 pk;
                #pragma unroll
                for (int r = 0; r < 4; r++) pk[r] = f2bf(acc[mi][ni][r] + bv);
                // vidx(key0+r,d) = vidx(key0,d)+r (key0%4==0 -> j-group stays)
                *(u16x4*)&Vb[(b * HH + h) * 131072 + vidx(key0, d)] = pk;
            } else if (which == 1) {
                #pragma unroll
                for (int r = 0; r < 4; r++) {
                    const int m = gm0 + mi * 16 + quad * 4 + r;
                    const int b = m >> 11, s = m & 2047;
                    Kb[(b * HH + h) * 131072 + kidx(s, d)] = f2bf(acc[mi][ni][r] + bv);
                }
            } else {
                #pragma unroll
                for (int r = 0; r < 4; r++) {
                    const int m = gm0 + mi * 16 + quad * 4 + r;
                    const int b = m >> 11, s = m & 2047;
                    Qb[((b * HH + h) * SS + s) * DD + d] = f2bf((acc[mi][ni][r] + bv) * QSCALE);
                }
            }
        }
    }
}

// ---------- 4. causal flash attention: 4 waves / 64 q-rows per block, 64-key LDS-staged tiles ----------
__global__ __launch_bounds__(256) void attn_kernel(
    const u16* __restrict__ Qb, const u16* __restrict__ Kb,
    const u16* __restrict__ Vb, u16* __restrict__ Ob)   // Ob: [B*S][E] bf16
{
    __shared__ __align__(16) u16 Ks[4096];          // 8 KB: 8 frag-blocks of 1KB (g*2+h)
    __shared__ __align__(16) u16 Vs[4096];          // 8 KB: 8 frag-blocks of 1KB (kg*4+dg)
    __shared__ __align__(16) u16 Plds[4 * 16 * 72]; // per-wave P, row-padded to 72
    const int tid = threadIdx.x;
    const int lane = tid & 63, wave = tid >> 6;
    const int lm = lane & 15, quad = lane >> 4;
    const int bh = blockIdx.x & 31;
    const int qt = 31 - (blockIdx.x >> 5);          // heavy q-tiles dispatch first
    const int q0 = qt * 64;
    const int b = bh >> 4, h = bh & 15;

    // Q A-fragments for this wave's 16 rows (scores come out pre-scaled by QSCALE)
    const u16* qbase = Qb + (bh * SS + q0 + wave * 16) * DD;
    const bf16x8 qf0 = ldb8(qbase + lm * DD + quad * 8);
    const bf16x8 qf1 = ldb8(qbase + lm * DD + 32 + quad * 8);

    const u16* ktile = Kb + bh * 131072;            // + kt*4096 per 64-key tile
    const u16* vtile = Vb + bh * 131072;
    u16* Pw = Plds + wave * (16 * 72);

    BfCast oc; oc.u = (u32x4){0x3F803F80u, 0x3F803F80u, 0x3F803F80u, 0x3F803F80u};
    const bf16x8 ones = oc.b;

    f32x4 oacc[4] = {};                             // O[row=quad*4+r][d = dg*16+lm]
    f32x4 lacc = {0.f, 0.f, 0.f, 0.f};              // row sums (via ones-MFMA)
    float mr[4] = {-INFINITY, -INFINITY, -INFINITY, -INFINITY};

    for (int kt = 0; kt <= qt; ++kt) {
        __syncthreads();                            // LDS safe to overwrite
        {
            // PER-LANE global source (+lane*8 u16 = lane*16B); wave-uniform LDS base
            const u16* ks = ktile + kt * 4096 + wave * 512 + lane * 8;
            const u16* vs = vtile + kt * 4096 + wave * 512 + lane * 8;
            gload16(ks,        Ks + wave * 512);
            gload16(ks + 2048, Ks + 2048 + wave * 512);
            gload16(vs,        Vs + wave * 512);
            gload16(vs + 2048, Vs + 2048 + wave * 512);
        }
        __syncthreads();                            // staged data visible

        // S = Q K^T  (4 key groups of 16, D=64 as two 32-contractions)
        f32x4 s[4];
        #pragma unroll
        for (int g = 0; g < 4; g++) {
            f32x4 z = {0.f, 0.f, 0.f, 0.f};
            z = __builtin_amdgcn_mfma_f32_16x16x32_bf16(qf0, ldb8(&Ks[(g * 2) * 512 + lane * 8]), z, 0, 0, 0);
            s[g] = __builtin_amdgcn_mfma_f32_16x16x32_bf16(qf1, ldb8(&Ks[(g * 2 + 1) * 512 + lane * 8]), z, 0, 0, 0);
        }
        if (kt == qt) {                             // diagonal tile: causal mask
            const int limit = wave * 16 + quad * 4;
            #pragma unroll
            for (int g = 0; g < 4; g++)
                #pragma unroll
                for (int r = 0; r < 4; r++)
                    if (g * 16 + lm > limit + r) s[g][r] = -INFINITY;
        }
        // row max (over 4 in-lane groups, then 16 lanes of lm)
        float cm[4];
        #pragma unroll
        for (int r = 0; r < 4; r++)
            cm[r] = fmaxf(fmaxf(s[0][r], s[1][r]), fmaxf(s[2][r], s[3][r]));
        #pragma unroll
        for (int off = 8; off >= 1; off >>= 1)
            #pragma unroll
            for (int r = 0; r < 4; r++) cm[r] = fmaxf(cm[r], __shfl_xor(cm[r], off));
        float alpha[4];
        #pragma unroll
        for (int r = 0; r < 4; r++) {
            const float mnew = fmaxf(mr[r], cm[r]);
            alpha[r] = __builtin_amdgcn_exp2f(mr[r] - mnew);
            mr[r] = mnew;
        }
        // P = exp2(S - m) -> per-wave LDS (C-layout -> A-layout transform)
        #pragma unroll
        for (int g = 0; g < 4; g++)
            #pragma unroll
            for (int r = 0; r < 4; r++)
                Pw[(quad * 4 + r) * 72 + g * 16 + lm] = f2bf(__builtin_amdgcn_exp2f(s[g][r] - mr[r]));
        const bf16x8 pf0 = ldb8(&Pw[lm * 72 + quad * 8]);
        const bf16x8 pf1 = ldb8(&Pw[lm * 72 + 32 + quad * 8]);
        // l = l*alpha + rowsum(P)  (ones-MFMA replaces shuffle-tree)
        #pragma unroll
        for (int r = 0; r < 4; r++) lacc[r] *= alpha[r];
        lacc = __builtin_amdgcn_mfma_f32_16x16x32_bf16(pf0, ones, lacc, 0, 0, 0);
        lacc = __builtin_amdgcn_mfma_f32_16x16x32_bf16(pf1, ones, lacc, 0, 0, 0);
        // O = O*alpha + P V
        #pragma unroll
        for (int dg = 0; dg < 4; dg++)
            #pragma unroll
            for (int r = 0; r < 4; r++) oacc[dg][r] *= alpha[r];
        #pragma unroll
        for (int dg = 0; dg < 4; dg++) {
            oacc[dg] = __builtin_amdgcn_mfma_f32_16x16x32_bf16(pf0, ldb8(&Vs[dg * 512 + lane * 8]), oacc[dg], 0, 0, 0);
            oacc[dg] = __builtin_amdgcn_mfma_f32_16x16x32_bf16(pf1, ldb8(&Vs[(4 + dg) * 512 + lane * 8]), oacc[dg], 0, 0, 0);
        }
    }
    // epilogue: O/l -> Ob[b*S+q][h*D+d] bf16
    u16* obase = Ob + (b * SS + q0 + wave * 16) * EE + h * DD;
    #pragma unroll
    for (int r = 0; r < 4; r++) {
        const float inv = 1.0f / lacc[r];
        u16* op = obase + (quad * 4 + r) * EE;
        #pragma unroll
        for (int dg = 0; dg < 4; dg++)
            op[dg * 16 + lm] = f2bf(oacc[dg][r] * inv);
    }
}

// ---------- 5. out-proj GEMM (128x128, BK=64): [4096,1024] x [1024,1024] + bias -> fp32 ----------
__global__ __launch_bounds__(256) void gemm_out_kernel(
    const u16* __restrict__ A,   // O bf16 [4096][1024]
    const u16* __restrict__ BT,  // W_out^T bf16 [1024][1024]
    const float* __restrict__ bias,
    float* __restrict__ Out)
{
    __shared__ __align__(16) u16 As[2 * BM * 32];
    __shared__ __align__(16) u16 Bs[2 * BN * 32];
    const int K = EE;
    const int lane = threadIdx.x & 63;
    const int wave = threadIdx.x >> 6;
    const int nb = EE / BN;                     // 8
    const int tm = blockIdx.x / nb, tn = blockIdx.x % nb;
    const int lm = lane & 15, quad = lane >> 4;

    const int srow = wave * 32 + (lane >> 2);
    const int scol = (lane & 3) * 8;
    const u16* ag = A  + (tm * BM + srow) * K + scol;
    const u16* bg = BT + (tn * BN + srow) * K + scol;
    u16* al = As + (wave * 32) * 32;
    u16* bl = Bs + (wave * 32) * 32;

    const int wy = wave >> 1, wx = wave & 1;
    f32x4 acc[4][4] = {};

    for (int k0 = 0; k0 < K; k0 += BK) {
        __syncthreads();
        gload16(ag,               al);
        gload16(ag + 16 * K,      al + 512);
        gload16(ag + 32,          al + 4096);
        gload16(ag + 32 + 16 * K, al + 4096 + 512);
        gload16(bg,               bl);
        gload16(bg + 16 * K,      bl + 512);
        gload16(bg + 32,          bl + 4096);
        gload16(bg + 32 + 16 * K, bl + 4096 + 512);
        ag += BK; bg += BK;
        __syncthreads();
        #pragma unroll
        for (int half = 0; half < 2; ++half) {
            const u16* Ah = As + half * 4096;
            const u16* Bh = Bs + half * 4096;
            bf16x8 af[4], bf[4];
            #pragma unroll
            for (int i = 0; i < 4; i++) {
                af[i] = ldb8(Ah + (wy * 64 + i * 16 + lm) * 32 + quad * 8);
                bf[i] = ldb8(Bh + (wx * 64 + i * 16 + lm) * 32 + quad * 8);
            }
            #pragma unroll
            for (int mi = 0; mi < 4; mi++)
                #pragma unroll
                for (int ni = 0; ni < 4; ni++)
                    acc[mi][ni] = __builtin_amdgcn_mfma_f32_16x16x32_bf16(af[mi], bf[ni], acc[mi][ni], 0, 0, 0);
        }
    }

    const int gm0 = tm * BM + wy * 64;
    const int gn0 = tn * BN + wx * 64;
    #pragma unroll
    for (int ni = 0; ni < 4; ni++) {
        const int n = gn0 + ni * 16 + lm;
        const float bv = bias[n];
        #pragma unroll
        for (int mi = 0; mi < 4; mi++)
            #pragma unroll
            for (int r = 0; r < 4; r++)
                Out[(gm0 + mi * 16 + quad * 4 + r) * EE + n] = acc[mi][ni][r] + bv;
    }
}

// ---------- launch ----------
extern "C" void kernel_launch(void* const* d_in, const int* in_sizes, int n_in,
                              void* d_out, int out_size, void* d_ws, size_t ws_size,
                              hipStream_t stream)
{
    const float* x     = (const float*)d_in[0];
    const float* Wqkv  = (const float*)d_in[1];
    const float* bqkv  = (const float*)d_in[2];
    const float* Wout  = (const float*)d_in[3];
    const float* bout  = (const float*)d_in[4];
    float* out = (float*)d_out;

    char* ws = (char*)d_ws;
    u16* xb    = (u16*)(ws + 0);          //  8 MB  x bf16 [4096][1024]
    u16* wqkvT = (u16*)(ws + 8388608);    //  6 MB  W_qkv^T bf16 [3072][1024]
    u16* woutT = (u16*)(ws + 14680064);   //  2 MB  W_out^T bf16 [1024][1024]
    u16* Qb    = (u16*)(ws + 16777216);   //  8 MB  [B,H,S,D] (pre-scaled)
    u16* Kb    = (u16*)(ws + 25165824);   //  8 MB  frag-ordered
    u16* Vb    = (u16*)(ws + 33554432);   //  8 MB  frag-ordered
    u16* Ob    = (u16*)(ws + 41943040);   //  8 MB  [B*S][E]
    if (ws_size < 50331648) return;       // need 48 MB

    conv_kernel<<<4096, 256, 0, stream>>>(x, xb, (BB * SS * EE) / 4);
    transpose_kernel<<<(EE / 32) * (3 * EE / 32), 256, 0, stream>>>(Wqkv, wqkvT, EE, 3 * EE);
    transpose_kernel<<<(EE / 32) * (EE / 32), 256, 0, stream>>>(Wout, woutT, EE, EE);
    gemm_qkv_kernel<<<(BB * SS / BM) * (3 * EE / BN), 256, 0, stream>>>(xb, wqkvT, bqkv, Qb, Kb, Vb);
    attn_kernel<<<BB * HH * (SS / 64), 256, 0, stream>>>(Qb, Kb, Vb, Ob);
    gemm_out_kernel<<<(BB * SS / BM) * (EE / BN), 256, 0, stream>>>(Ob, woutT, bout, out);
}